// Round 12
// baseline (247.434 us; speedup 1.0000x reference)
//
#include <hip/hip_runtime.h>
#include <stdint.h>

#define BB 2
#define NN 2048
#define EE 768
#define HH 12
#define DD 64
#define GG 16

typedef unsigned short u16;
typedef unsigned int u32;
typedef __attribute__((ext_vector_type(8))) short short8;
typedef __attribute__((ext_vector_type(4))) float f32x4;
typedef __attribute__((ext_vector_type(4))) unsigned short u16x4;

__device__ __forceinline__ u16 f2bf(float f) {
  union { float f; u32 u; } a; a.f = f;
  u32 r = a.u + 0x7FFFu + ((a.u >> 16) & 1u);
  return (u16)(r >> 16);
}
__device__ __forceinline__ float bf2f(short s) {
  union { u32 u; float f; } a; a.u = ((u32)(u16)s) << 16; return a.f;
}

__device__ __forceinline__ float silu_f(float v) { return v / (1.f + __expf(-v)); }

__device__ __forceinline__ void gload16(const u16* g, char* l) {
  __builtin_amdgcn_global_load_lds(
      (const __attribute__((address_space(1))) void*)(g),
      (__attribute__((address_space(3))) void*)(l), 16, 0, 0);
}

// Stage a ROWS x 64 bf16 tile (row-major source, leading dim ld) into LDS.
// 16B chunks, XOR-swizzled within each row so fragment reads are ~conflict-free.
template<int ROWS>
__device__ __forceinline__ void stage_tile(const u16* __restrict__ gb, int ld, int row0, int col0,
                                           char* lds, int tid) {
  int wid = tid >> 6;
#pragma unroll
  for (int it = 0; it < ROWS / 32; ++it) {
    int c = it * 256 + tid;
    int r = c >> 3;
    int g = (c & 7) ^ (r & 7);
    gload16(gb + (size_t)(row0 + r) * ld + col0 + g * 8,
            lds + (it * 256 + wid * 64) * 16);  // wave-uniform base; HW adds lane*16
  }
}

// Stage a 64x64 bf16 plane stored as 4 quarters (16 rows each): quarter q at
// u16 offset q*2048, plane (hi=0/lo=1) at +plane*1024 within the quarter.
__device__ __forceinline__ void stage_S(const u16* __restrict__ base, char* lds, int tid, int plane) {
  int wid = tid >> 6;
#pragma unroll
  for (int it = 0; it < 2; ++it) {
    int c = it * 256 + tid;
    int r = c >> 3;
    int g = (c & 7) ^ (r & 7);
    gload16(base + (r >> 4) * 2048 + plane * 1024 + (r & 15) * 64 + g * 8,
            lds + (it * 256 + wid * 64) * 16);
  }
}

__device__ __forceinline__ short8 read_frag(const char* lds, int row, int gk) {
  return *(const short8*)(lds + (((row << 3) | (gk ^ (row & 7))) << 4));
}

__device__ __forceinline__ short8 scale_frag(short8 f, float sc) {
  short8 o;
#pragma unroll
  for (int i = 0; i < 8; ++i) o[i] = (short)f2bf(bf2f(f[i]) * sc);
  return o;
}

// ---------------- fused prep: W^T bf16 | (t = x @ Wg1  +  x->bf16, x read once) ----------------
// blockIdx.x ranges (block-uniform branch): [0,576) wconv, [576,1600) tg+xconv
__global__ __launch_bounds__(256) void prep_kernel(const float* __restrict__ x,
    const float* __restrict__ Wq, const float* __restrict__ Wk, const float* __restrict__ Wv,
    const float* __restrict__ Wo, const float* __restrict__ Wg1,
    u16* __restrict__ xb, u16* __restrict__ Wqt, u16* __restrict__ Wkt,
    u16* __restrict__ Wvt, u16* __restrict__ Wot, float* __restrict__ tgp) {
  __shared__ float tb[64][65];
  int gx = blockIdx.x, tid = threadIdx.x;
  if (gx < 576) {
    // ---- W (768x768 f32) -> W^T bf16
    int z = gx / 144, rem = gx % 144;
    int kx = rem / 12, ny = rem % 12;
    const float* src; u16* dst;
    if (z == 0)      { src = Wq; dst = Wqt; }
    else if (z == 1) { src = Wk; dst = Wkt; }
    else if (z == 2) { src = Wv; dst = Wvt; }
    else             { src = Wo; dst = Wot; }
    int k0 = kx * 64, n0 = ny * 64;
#pragma unroll
    for (int i = 0; i < 16; ++i) {
      int idx = i * 256 + tid;
      int r = idx >> 6, c = idx & 63;
      tb[r][c] = src[(size_t)(k0 + r) * EE + n0 + c];
    }
    __syncthreads();
#pragma unroll
    for (int i = 0; i < 16; ++i) {
      int idx = i * 256 + tid;
      int rn = idx >> 6, ck = idx & 63;
      dst[(size_t)(n0 + rn) * EE + k0 + ck] = f2bf(tb[ck][rn]);
    }
  } else {
    // ---- one wave per x-row: emit bf16 row + t = row @ Wg1 (fp32 exact)
    int lane = tid & 63, wid = tid >> 6;
    int m = (gx - 576) * 4 + wid;
    const float* xr = x + (size_t)m * EE;
#pragma unroll
    for (int j = 0; j < 3; ++j) {
      float4 v = ((const float4*)xr)[lane + 64 * j];
      u16x4 o;
      o.x = f2bf(v.x); o.y = f2bf(v.y); o.z = f2bf(v.z); o.w = f2bf(v.w);
      ((u16x4*)(xb + (size_t)m * EE))[lane + 64 * j] = o;
    }
    int col = lane & 15, sl = lane >> 4;
    const float* xs = xr + sl * 192;
    float acc = 0.f;
#pragma unroll 4
    for (int i = 0; i < 48; ++i) {
      float4 xv = ((const float4*)xs)[i];
      int kk = sl * 192 + i * 4;
      acc += xv.x * Wg1[(kk + 0) * GG + col];
      acc += xv.y * Wg1[(kk + 1) * GG + col];
      acc += xv.z * Wg1[(kk + 2) * GG + col];
      acc += xv.w * Wg1[(kk + 3) * GG + col];
    }
    acc += __shfl_down(acc, 32);
    acc += __shfl_down(acc, 16);
    if (lane < 16) tgp[(size_t)m * GG + col] = acc;
  }
}

// ---------------- QKV projection (128x128 tile, 1-D grid, m-fastest for XCD locality) ----------------
// XCD = bid % 8 = m % 8 (32 m-tiles, 32 % 8 == 0): all 18 blocks (6 n x 3 w) sharing one
// x m-tile land on ONE XCD -> x re-reads hit that XCD's L2 instead of L3.
__global__ __launch_bounds__(256) void qkv_gemm(const u16* __restrict__ xb,
    const u16* __restrict__ Wqt, const u16* __restrict__ Wkt, const u16* __restrict__ Wvt,
    u16* __restrict__ qp, u16* __restrict__ kp, u16* __restrict__ ktp, u16* __restrict__ vtp) {
  __shared__ __attribute__((aligned(16))) char As[16384];
  __shared__ __attribute__((aligned(16))) char Zs[16384];
  int tid = threadIdx.x, lane = tid & 63, wid = tid >> 6;
  int quad = lane >> 4, l15 = lane & 15;
  int bid = blockIdx.x;
  int m0 = (bid & 31) * 128;
  int nw = bid >> 5;
  int n0 = (nw % 6) * 128, w = nw / 6;
  const u16* Zt = (w == 0) ? Wqt : (w == 1) ? Wkt : Wvt;
  int wm = wid >> 1, wn = wid & 1;
  f32x4 acc[4][4] = {};
  for (int kt = 0; kt < EE / 64; ++kt) {
    __syncthreads();
    stage_tile<128>(xb, EE, m0, kt * 64, As, tid);
    stage_tile<128>(Zt, EE, n0, kt * 64, Zs, tid);
    __syncthreads();
    short8 af[2][4], bfr[2][4];
#pragma unroll
    for (int ds = 0; ds < 2; ++ds) {
      int gk = ds * 4 + quad;
#pragma unroll
      for (int i = 0; i < 4; ++i) {
        af[ds][i]  = read_frag(As, wm * 64 + i * 16 + l15, gk);
        bfr[ds][i] = read_frag(Zs, wn * 64 + i * 16 + l15, gk);
      }
    }
#pragma unroll
    for (int mi = 0; mi < 4; ++mi)
#pragma unroll
      for (int ni = 0; ni < 4; ++ni) {
        acc[mi][ni] = __builtin_amdgcn_mfma_f32_16x16x32_bf16(af[0][mi], bfr[0][ni], acc[mi][ni], 0, 0, 0);
        acc[mi][ni] = __builtin_amdgcn_mfma_f32_16x16x32_bf16(af[1][mi], bfr[1][ni], acc[mi][ni], 0, 0, 0);
      }
  }
#pragma unroll
  for (int mi = 0; mi < 4; ++mi) {
    int mbase = m0 + wm * 64 + mi * 16 + (quad << 2);
    int bidx = mbase >> 11, nbase = mbase & 2047;
#pragma unroll
    for (int ni = 0; ni < 4; ++ni) {
      int e = n0 + wn * 64 + ni * 16 + l15;
      int h = e >> 6, d = e & 63;
      u16 v0 = f2bf(silu_f(acc[mi][ni][0]));
      u16 v1 = f2bf(silu_f(acc[mi][ni][1]));
      u16 v2 = f2bf(silu_f(acc[mi][ni][2]));
      u16 v3 = f2bf(silu_f(acc[mi][ni][3]));
      if (w < 2) {
        u16* dst = (w == 0 ? qp : kp) + (size_t)(bidx * HH + h) * NN * DD + d;
        dst[(size_t)(nbase + 0) * DD] = v0;
        dst[(size_t)(nbase + 1) * DD] = v1;
        dst[(size_t)(nbase + 2) * DD] = v2;
        dst[(size_t)(nbase + 3) * DD] = v3;
        if (w == 1) {  // K^T for lstate
          u16x4 pk; pk.x = v0; pk.y = v1; pk.z = v2; pk.w = v3;
          *(u16x4*)(ktp + (size_t)((bidx * HH + h) * DD + d) * NN + nbase) = pk;
        }
      } else {
        u16x4 pk; pk.x = v0; pk.y = v1; pk.z = v2; pk.w = v3;
        *(u16x4*)(vtp + (size_t)((bidx * HH + h) * DD + d) * NN + nbase) = pk;
      }
    }
  }
}

// ---------------- pass A: per-chunk local decayed KV state (bf16 hi/lo out, halves traffic) ----------------
// L[d'][d] = sum_j (v_j[d'] * e^{s(64-jl)}) * k_j[d]; written as hi/lo bf16 planes in the
// quarter layout (quarter=row>>4 at *2048, lo plane +1024, row at *64) -> 12.6 MB not 25.
__global__ __launch_bounds__(256) void lstate_kernel(const u16* __restrict__ ktp,
    const u16* __restrict__ vtp, const float* __restrict__ slopes, u16* __restrict__ Lb) {
  __shared__ __attribute__((aligned(16))) char KTs[8192];
  __shared__ __attribute__((aligned(16))) char VTs[8192];
  int tid = threadIdx.x, lane = tid & 63, wid = tid >> 6;
  int quad = lane >> 4, l15 = lane & 15;
  int c = blockIdx.x, bh = blockIdx.y, h = bh % HH;
  float slope = slopes[h];
  const u16* ktb = ktp + (size_t)bh * DD * NN;
  const u16* vtb = vtp + (size_t)bh * DD * NN;
  stage_tile<64>(vtb, NN, 0, c * 64, VTs, tid);
  stage_tile<64>(ktb, NN, 0, c * 64, KTs, tid);
  __syncthreads();
  f32x4 acc[4] = {};
  float em = __expf(-slope);  // > 1, <= ~1.9
#pragma unroll
  for (int ks = 0; ks < 2; ++ks) {
    int kg = ks * 4 + quad;
    short8 vf = read_frag(VTs, wid * 16 + l15, kg);
    float f = __expf(slope * (float)(64 - kg * 8));
    short8 vdf;
#pragma unroll
    for (int jj = 0; jj < 8; ++jj) { vdf[jj] = (short)f2bf(bf2f(vf[jj]) * f); f *= em; }
#pragma unroll
    for (int dt = 0; dt < 4; ++dt)
      acc[dt] = __builtin_amdgcn_mfma_f32_16x16x32_bf16(
          vdf, read_frag(KTs, dt * 16 + l15, kg), acc[dt], 0, 0, 0);
  }
  u16* Lo = Lb + ((size_t)bh * 32 + c) * 8192;
#pragma unroll
  for (int dt = 0; dt < 4; ++dt)
#pragma unroll
    for (int r = 0; r < 4; ++r) {
      float a = acc[dt][r];
      u16 hv = f2bf(a);
      u16 lv = f2bf(a - bf2f((short)hv));
      int row = wid * 16 + quad * 4 + r;
      int idx = (row >> 4) * 2048 + (row & 15) * 64 + dt * 16 + l15;
      Lo[idx] = hv;
      Lo[idx + 1024] = lv;
    }
}

// ---------------- scan: exclusive decayed prefix of chunk states ----------------
// S_{c+1} = S_c * e^{64s} + L_c; reads bf16 hi/lo L (fp32 accumulate), writes bf16 hi/lo
// to SEPARATE Sst (slot c holds S_{c+1}). No aliasing -> no barriers -> 8-deep raw
// prefetch ring (hi/lo kept as u16x4 in the ring; combined only at consumption so the
// loads stay independent and in flight).
__global__ __launch_bounds__(256) void scan_kernel(const u16* __restrict__ Lb,
    float* __restrict__ Sst, const float* __restrict__ slopes) {
  int g = blockIdx.x, bh = blockIdx.y, h = bh % HH, t = threadIdx.x;
  float D = __expf(slopes[h] * 64.f);
  const u16* base = Lb + (size_t)bh * 32 * 8192;
  float* obase = Sst + (size_t)bh * 32 * 4096;
  int wo = g * 2048 + (t >> 4) * 64 + (t & 15) * 4;
  float4 acc = {0.f, 0.f, 0.f, 0.f};
  u16x4 rh[8], rl[8];
#pragma unroll
  for (int i = 0; i < 8; ++i) {
    rh[i] = *(const u16x4*)(base + (size_t)i * 8192 + wo);
    rl[i] = *(const u16x4*)(base + (size_t)i * 8192 + wo + 1024);
  }
  for (int c = 0; c < 31; ++c) {
    u16x4 ch = rh[c & 7], cl = rl[c & 7];
    if (c + 8 < 31) {
      rh[c & 7] = *(const u16x4*)(base + (size_t)(c + 8) * 8192 + wo);
      rl[c & 7] = *(const u16x4*)(base + (size_t)(c + 8) * 8192 + wo + 1024);
    }
    acc.x = acc.x * D + (bf2f((short)ch.x) + bf2f((short)cl.x));
    acc.y = acc.y * D + (bf2f((short)ch.y) + bf2f((short)cl.y));
    acc.z = acc.z * D + (bf2f((short)ch.z) + bf2f((short)cl.z));
    acc.w = acc.w * D + (bf2f((short)ch.w) + bf2f((short)cl.w));
    float a[4] = {acc.x, acc.y, acc.z, acc.w};
    u16 hv[4], lv[4];
#pragma unroll
    for (int i = 0; i < 4; ++i) {
      hv[i] = f2bf(a[i]);
      lv[i] = f2bf(a[i] - bf2f((short)hv[i]));
    }
    u16x4 hi, lo;
    hi.x = hv[0]; hi.y = hv[1]; hi.z = hv[2]; hi.w = hv[3];
    lo.x = lv[0]; lo.y = lv[1]; lo.z = lv[2]; lo.w = lv[3];
    u16* sb = (u16*)(obase + (size_t)c * 4096);
    *(u16x4*)(sb + wo) = hi;
    *(u16x4*)(sb + wo + 1024) = lo;
  }
}

// ---------------- pass B: intra-chunk attn + q_decayed @ S_prev + fused output gate ----------------
__global__ __launch_bounds__(256) void attn_chunk(const u16* __restrict__ qp,
    const u16* __restrict__ kp, const u16* __restrict__ vtp,
    const float* __restrict__ slopes, const float* __restrict__ Sst,
    const float* __restrict__ tgp, const float* __restrict__ Wg2, u16* __restrict__ attnb) {
  __shared__ __attribute__((aligned(16))) char Ks[8192];
  __shared__ __attribute__((aligned(16))) char Vs[8192];
  __shared__ __attribute__((aligned(16))) char Sh[8192];
  __shared__ __attribute__((aligned(16))) char Sl[8192];
  __shared__ __attribute__((aligned(16))) char Ps[4][2304];  // per-wave P, 16 rows x 144B stride
  __shared__ float ts[64][16];   // gate t rows for this q-chunk
  __shared__ float w2[16][64];   // Wg2 columns for this head
  int tid = threadIdx.x, lane = tid & 63, wid = tid >> 6;
  int quad = lane >> 4, l15 = lane & 15;
  int c = blockIdx.x, bh = blockIdx.y, b = bh / HH, h = bh % HH;
  float slope = slopes[h];
  int q0 = c * 64;
  const u16* qbh = qp + (size_t)bh * NN * DD;
  const u16* kbh = kp + (size_t)bh * NN * DD;
  const u16* vbh = vtp + (size_t)bh * DD * NN;

  stage_tile<64>(kbh, DD, q0, 0, Ks, tid);   // K chunk: 64 keys x 64 d
  stage_tile<64>(vbh, NN, 0, q0, Vs, tid);   // V^T chunk: 64 d x 64 keys
  if (c > 0) {
    const u16* sb = (const u16*)(Sst + ((size_t)bh * 32 + (c - 1)) * 4096);
    stage_S(sb, Sh, tid, 0);
    stage_S(sb, Sl, tid, 1);
  }
  // gate operands: t rows (64x16) and Wg2 slab (16x64)
  {
    float4 tv = *(const float4*)(tgp + ((size_t)(b * NN + q0) + (tid >> 2)) * GG + (tid & 3) * 4);
    *(float4*)&ts[tid >> 2][(tid & 3) * 4] = tv;
    float4 wv = *(const float4*)(Wg2 + (size_t)(tid >> 4) * EE + h * 64 + (tid & 15) * 4);
    *(float4*)&w2[tid >> 4][(tid & 15) * 4] = wv;
  }
  int qrow = q0 + wid * 16 + l15;
  short8 qf0 = *(const short8*)(qbh + (size_t)qrow * DD + (quad << 3));
  short8 qf1 = *(const short8*)(qbh + (size_t)qrow * DD + 32 + (quad << 3));
  __syncthreads();

  f32x4 oacc[4] = {};
  char* Pw = Ps[wid];
  int qbase = q0 + wid * 16 + (quad << 2);

  // ---- intra-chunk: S = QK^T . decay, P -> A-layout via wave-private LDS, O += P V
  float t_hi = (float)(q0 + 63);
  float rex[4];
#pragma unroll
  for (int r = 0; r < 4; ++r) rex[r] = __expf(slope * ((float)(qbase + r) - t_hi));
#pragma unroll
  for (int jt = 0; jt < 4; ++jt) {
    f32x4 s = {};
    s = __builtin_amdgcn_mfma_f32_16x16x32_bf16(qf0, read_frag(Ks, jt * 16 + l15, quad), s, 0, 0, 0);
    s = __builtin_amdgcn_mfma_f32_16x16x32_bf16(qf1, read_frag(Ks, jt * 16 + l15, 4 + quad), s, 0, 0, 0);
    int jg = q0 + jt * 16 + l15;
    float cex = __expf(slope * (t_hi - (float)jg));
#pragma unroll
    for (int r = 0; r < 4; ++r) {
      int diff = qbase + r - jg;
      float val = (diff >= 0) ? s[r] * rex[r] * cex : 0.f;
      *(u16*)(Pw + (((quad << 2) + r) * 72 + jt * 16 + l15) * 2) = f2bf(val);
    }
  }
  __asm__ volatile("s_waitcnt lgkmcnt(0)" ::: "memory");
#pragma unroll
  for (int ks = 0; ks < 2; ++ks) {
    short8 pf = *(const short8*)(Pw + l15 * 144 + ks * 64 + (quad << 4));
#pragma unroll
    for (int dt = 0; dt < 4; ++dt) {
      oacc[dt] = __builtin_amdgcn_mfma_f32_16x16x32_bf16(
          pf, read_frag(Vs, dt * 16 + l15, ks * 4 + quad), oacc[dt], 0, 0, 0);
    }
  }

  // ---- inter-chunk: O += (e^{s*il} q) @ S_prev  (hi + lo planes)
  if (c > 0) {
    int il = wid * 16 + l15;
    float qsc = __expf(slope * (float)il);
    short8 qd0 = scale_frag(qf0, qsc);
    short8 qd1 = scale_frag(qf1, qsc);
#pragma unroll
    for (int dt = 0; dt < 4; ++dt) {
      oacc[dt] = __builtin_amdgcn_mfma_f32_16x16x32_bf16(qd0, read_frag(Sh, dt * 16 + l15, quad), oacc[dt], 0, 0, 0);
      oacc[dt] = __builtin_amdgcn_mfma_f32_16x16x32_bf16(qd1, read_frag(Sh, dt * 16 + l15, 4 + quad), oacc[dt], 0, 0, 0);
      oacc[dt] = __builtin_amdgcn_mfma_f32_16x16x32_bf16(qd0, read_frag(Sl, dt * 16 + l15, quad), oacc[dt], 0, 0, 0);
      oacc[dt] = __builtin_amdgcn_mfma_f32_16x16x32_bf16(qd1, read_frag(Sl, dt * 16 + l15, 4 + quad), oacc[dt], 0, 0, 0);
    }
  }

  // ---- fused low-rank output gate: O *= sigmoid(t @ Wg2) for this head's slab
#pragma unroll
  for (int r = 0; r < 4; ++r) {
    int row = wid * 16 + (quad << 2) + r;
    float gv[4] = {0.f, 0.f, 0.f, 0.f};
#pragma unroll
    for (int g = 0; g < 16; ++g) {
      float tv = ts[row][g];
#pragma unroll
      for (int dt = 0; dt < 4; ++dt) gv[dt] += tv * w2[g][dt * 16 + l15];
    }
#pragma unroll
    for (int dt = 0; dt < 4; ++dt)
      oacc[dt][r] *= 1.f / (1.f + __expf(-gv[dt]));
  }

#pragma unroll
  for (int dt = 0; dt < 4; ++dt)
#pragma unroll
    for (int r = 0; r < 4; ++r) {
      int qi = qbase + r;
      int e = h * 64 + dt * 16 + l15;
      attnb[(size_t)(b * NN + qi) * EE + e] = f2bf(oacc[dt][r]);
    }
}

// ---------------- y = gated @ Wo (64x128 tile, 1-D grid m-fastest, bf16 out) ----------------
// XCD = bid % 8 = m % 8: the 6 n-blocks sharing an A m-tile co-locate on one XCD.
__global__ __launch_bounds__(256) void wo_gemm(const u16* __restrict__ A, const u16* __restrict__ Zt,
                                               u16* __restrict__ Y) {
  __shared__ __attribute__((aligned(16))) char As[8192];
  __shared__ __attribute__((aligned(16))) char Zs[16384];
  int tid = threadIdx.x, lane = tid & 63, wid = tid >> 6;
  int quad = lane >> 4, l15 = lane & 15;
  int bid = blockIdx.x;
  int m0 = (bid & 63) * 64, n0 = (bid >> 6) * 128;
  int wm = wid >> 1, wn = wid & 1;
  f32x4 acc[2][4] = {};
  for (int kt = 0; kt < EE / 64; ++kt) {
    __syncthreads();
    stage_tile<64>(A, EE, m0, kt * 64, As, tid);
    stage_tile<128>(Zt, EE, n0, kt * 64, Zs, tid);
    __syncthreads();
    short8 af[2][2], bfr[2][4];
#pragma unroll
    for (int ds = 0; ds < 2; ++ds) {
      int gk = ds * 4 + quad;
#pragma unroll
      for (int i = 0; i < 2; ++i)
        af[ds][i] = read_frag(As, wm * 32 + i * 16 + l15, gk);
#pragma unroll
      for (int i = 0; i < 4; ++i)
        bfr[ds][i] = read_frag(Zs, wn * 64 + i * 16 + l15, gk);
    }
#pragma unroll
    for (int mi = 0; mi < 2; ++mi)
#pragma unroll
      for (int ni = 0; ni < 4; ++ni) {
        acc[mi][ni] = __builtin_amdgcn_mfma_f32_16x16x32_bf16(af[0][mi], bfr[0][ni], acc[mi][ni], 0, 0, 0);
        acc[mi][ni] = __builtin_amdgcn_mfma_f32_16x16x32_bf16(af[1][mi], bfr[1][ni], acc[mi][ni], 0, 0, 0);
      }
  }
#pragma unroll
  for (int mi = 0; mi < 2; ++mi) {
    int mbase = m0 + wm * 32 + mi * 16 + (quad << 2);
#pragma unroll
    for (int ni = 0; ni < 4; ++ni) {
      int e = n0 + wn * 64 + ni * 16 + l15;
#pragma unroll
      for (int r = 0; r < 4; ++r)
        Y[(size_t)(mbase + r) * EE + e] = f2bf(acc[mi][ni][r]);
    }
  }
}

// ---------------- layernorm over E=768 (bf16 in, fp32 out), one block per row ----------------
__global__ __launch_bounds__(256) void ln_kernel(const u16* __restrict__ y, const float* __restrict__ w,
    const float* __restrict__ bb, float* __restrict__ out) {
  int m = blockIdx.x, tid = threadIdx.x;
  const u16* yr = y + (size_t)m * EE;
  float v0 = bf2f((short)yr[tid]), v1 = bf2f((short)yr[tid + 256]), v2 = bf2f((short)yr[tid + 512]);
  float s = v0 + v1 + v2;
  float s2 = v0 * v0 + v1 * v1 + v2 * v2;
#pragma unroll
  for (int off = 32; off > 0; off >>= 1) {
    s += __shfl_down(s, off);
    s2 += __shfl_down(s2, off);
  }
  __shared__ float ss[4], ssq[4];
  int lane = tid & 63, wid = tid >> 6;
  if (lane == 0) { ss[wid] = s; ssq[wid] = s2; }
  __syncthreads();
  s = ss[0] + ss[1] + ss[2] + ss[3];
  s2 = ssq[0] + ssq[1] + ssq[2] + ssq[3];
  float mu = s * (1.f / 768.f);
  float var = s2 * (1.f / 768.f) - mu * mu;
  float rs = rsqrtf(var + 1e-5f);
  float* orow = out + (size_t)m * EE;
  orow[tid]       = (v0 - mu) * rs * w[tid]       + bb[tid];
  orow[tid + 256] = (v1 - mu) * rs * w[tid + 256] + bb[tid + 256];
  orow[tid + 512] = (v2 - mu) * rs * w[tid + 512] + bb[tid + 512];
}

extern "C" void kernel_launch(void* const* d_in, const int* in_sizes, int n_in,
                              void* d_out, int out_size, void* d_ws, size_t ws_size,
                              hipStream_t stream) {
  (void)in_sizes; (void)n_in; (void)out_size; (void)ws_size;
  const float* x   = (const float*)d_in[0];
  const float* ls  = (const float*)d_in[1];
  const float* Wq  = (const float*)d_in[2];
  const float* Wk  = (const float*)d_in[3];
  const float* Wv  = (const float*)d_in[4];
  const float* Wo  = (const float*)d_in[5];
  const float* Wg1 = (const float*)d_in[6];
  const float* Wg2 = (const float*)d_in[7];
  const float* lnw = (const float*)d_in[8];
  const float* lnb = (const float*)d_in[9];

  // Workspace: high-water 61603840 B (ws proven 268 MB via fill WRITE_SIZE).
  char* p = (char*)d_ws;
  u16* xb    = (u16*)(p + 0);          // 6291456 B (xb -> attnb)
  u16* attnb = (u16*)(p + 0);
  u16* Wqt   = (u16*)(p + 6291456);
  u16* Wkt   = (u16*)(p + 7471104);
  u16* Wvt   = (u16*)(p + 8650752);
  u16* Wot   = (u16*)(p + 9830400);
  u16* qq    = (u16*)(p + 11010048);   // reused as yy (bf16) after attn
  u16* kk    = (u16*)(p + 17301504);
  u16* vt    = (u16*)(p + 23592960);
  float* tg  = (float*)(p + 29884416); // 262144 B
  u16* Lb    = (u16*)(p + 30146560);   // 12582912 B: bf16 hi/lo chunk states L
  u16* kt2   = (u16*)(p + 42729472);   // 6291456 B: K^T
  float* Sst = (float*)(p + 49020928); // 12582912 B: bf16 hi/lo S planes (end 61603840)
  u16* yy    = (u16*)(p + 11010048);   // bf16 y (dead qq region)
  float* out = (float*)d_out;

  hipLaunchKernelGGL(prep_kernel, dim3(1600), dim3(256), 0, stream, x, Wq, Wk, Wv, Wo, Wg1,
                     xb, Wqt, Wkt, Wvt, Wot, tg);
  hipLaunchKernelGGL(qkv_gemm, dim3(576), dim3(256), 0, stream, xb, Wqt, Wkt, Wvt, qq, kk, kt2, vt);
  hipLaunchKernelGGL(lstate_kernel, dim3(32, 24), dim3(256), 0, stream, kt2, vt, ls, Lb);
  hipLaunchKernelGGL(scan_kernel, dim3(4, 24), dim3(256), 0, stream, Lb, Sst, ls);
  hipLaunchKernelGGL(attn_chunk, dim3(32, 24), dim3(256), 0, stream, qq, kk, vt, ls, Sst, tg, Wg2, attnb);
  hipLaunchKernelGGL(wo_gemm, dim3(384), dim3(256), 0, stream, attnb, Wot, yy);
  hipLaunchKernelGGL(ln_kernel, dim3(4096), dim3(256), 0, stream, yy, lnw, lnb, out);
}

// Round 13
// 164.684 us; speedup vs baseline: 1.5025x; 1.5025x over previous
//
#include <hip/hip_runtime.h>
#include <stdint.h>

#define BB 2
#define NN 2048
#define EE 768
#define HH 12
#define DD 64
#define GG 16

typedef unsigned short u16;
typedef unsigned int u32;
typedef __attribute__((ext_vector_type(8))) short short8;
typedef __attribute__((ext_vector_type(4))) float f32x4;
typedef __attribute__((ext_vector_type(4))) unsigned short u16x4;

__device__ __forceinline__ u16 f2bf(float f) {
  union { float f; u32 u; } a; a.f = f;
  u32 r = a.u + 0x7FFFu + ((a.u >> 16) & 1u);
  return (u16)(r >> 16);
}
__device__ __forceinline__ float bf2f(short s) {
  union { u32 u; float f; } a; a.u = ((u32)(u16)s) << 16; return a.f;
}

__device__ __forceinline__ float silu_f(float v) { return v / (1.f + __expf(-v)); }

__device__ __forceinline__ void gload16(const u16* g, char* l) {
  __builtin_amdgcn_global_load_lds(
      (const __attribute__((address_space(1))) void*)(g),
      (__attribute__((address_space(3))) void*)(l), 16, 0, 0);
}

// Stage a ROWS x 64 bf16 tile (row-major source, leading dim ld) into LDS.
// 16B chunks, XOR-swizzled within each row so fragment reads are ~conflict-free.
template<int ROWS>
__device__ __forceinline__ void stage_tile(const u16* __restrict__ gb, int ld, int row0, int col0,
                                           char* lds, int tid) {
  int wid = tid >> 6;
#pragma unroll
  for (int it = 0; it < ROWS / 32; ++it) {
    int c = it * 256 + tid;
    int r = c >> 3;
    int g = (c & 7) ^ (r & 7);
    gload16(gb + (size_t)(row0 + r) * ld + col0 + g * 8,
            lds + (it * 256 + wid * 64) * 16);  // wave-uniform base; HW adds lane*16
  }
}

// Stage a 64x64 bf16 plane stored as 4 quarters (16 rows each): quarter q at
// u16 offset q*2048, plane (hi=0/lo=1) at +plane*1024 within the quarter.
__device__ __forceinline__ void stage_S(const u16* __restrict__ base, char* lds, int tid, int plane) {
  int wid = tid >> 6;
#pragma unroll
  for (int it = 0; it < 2; ++it) {
    int c = it * 256 + tid;
    int r = c >> 3;
    int g = (c & 7) ^ (r & 7);
    gload16(base + (r >> 4) * 2048 + plane * 1024 + (r & 15) * 64 + g * 8,
            lds + (it * 256 + wid * 64) * 16);
  }
}

__device__ __forceinline__ short8 read_frag(const char* lds, int row, int gk) {
  return *(const short8*)(lds + (((row << 3) | (gk ^ (row & 7))) << 4));
}

__device__ __forceinline__ short8 scale_frag(short8 f, float sc) {
  short8 o;
#pragma unroll
  for (int i = 0; i < 8; ++i) o[i] = (short)f2bf(bf2f(f[i]) * sc);
  return o;
}

// ---------------- fused prep: W^T bf16 | (t = x @ Wg1  +  x->bf16, x read once) ----------------
// blockIdx.x ranges (block-uniform branch): [0,576) wconv, [576,1600) tg+xconv
__global__ __launch_bounds__(256) void prep_kernel(const float* __restrict__ x,
    const float* __restrict__ Wq, const float* __restrict__ Wk, const float* __restrict__ Wv,
    const float* __restrict__ Wo, const float* __restrict__ Wg1,
    u16* __restrict__ xb, u16* __restrict__ Wqt, u16* __restrict__ Wkt,
    u16* __restrict__ Wvt, u16* __restrict__ Wot, float* __restrict__ tgp) {
  __shared__ float tb[64][65];
  int gx = blockIdx.x, tid = threadIdx.x;
  if (gx < 576) {
    // ---- W (768x768 f32) -> W^T bf16
    int z = gx / 144, rem = gx % 144;
    int kx = rem / 12, ny = rem % 12;
    const float* src; u16* dst;
    if (z == 0)      { src = Wq; dst = Wqt; }
    else if (z == 1) { src = Wk; dst = Wkt; }
    else if (z == 2) { src = Wv; dst = Wvt; }
    else             { src = Wo; dst = Wot; }
    int k0 = kx * 64, n0 = ny * 64;
#pragma unroll
    for (int i = 0; i < 16; ++i) {
      int idx = i * 256 + tid;
      int r = idx >> 6, c = idx & 63;
      tb[r][c] = src[(size_t)(k0 + r) * EE + n0 + c];
    }
    __syncthreads();
#pragma unroll
    for (int i = 0; i < 16; ++i) {
      int idx = i * 256 + tid;
      int rn = idx >> 6, ck = idx & 63;
      dst[(size_t)(n0 + rn) * EE + k0 + ck] = f2bf(tb[ck][rn]);
    }
  } else {
    // ---- one wave per x-row: emit bf16 row + t = row @ Wg1 (fp32 exact)
    int lane = tid & 63, wid = tid >> 6;
    int m = (gx - 576) * 4 + wid;
    const float* xr = x + (size_t)m * EE;
#pragma unroll
    for (int j = 0; j < 3; ++j) {
      float4 v = ((const float4*)xr)[lane + 64 * j];
      u16x4 o;
      o.x = f2bf(v.x); o.y = f2bf(v.y); o.z = f2bf(v.z); o.w = f2bf(v.w);
      ((u16x4*)(xb + (size_t)m * EE))[lane + 64 * j] = o;
    }
    int col = lane & 15, sl = lane >> 4;
    const float* xs = xr + sl * 192;
    float acc = 0.f;
#pragma unroll 4
    for (int i = 0; i < 48; ++i) {
      float4 xv = ((const float4*)xs)[i];
      int kk = sl * 192 + i * 4;
      acc += xv.x * Wg1[(kk + 0) * GG + col];
      acc += xv.y * Wg1[(kk + 1) * GG + col];
      acc += xv.z * Wg1[(kk + 2) * GG + col];
      acc += xv.w * Wg1[(kk + 3) * GG + col];
    }
    acc += __shfl_down(acc, 32);
    acc += __shfl_down(acc, 16);
    if (lane < 16) tgp[(size_t)m * GG + col] = acc;
  }
}

// ---------------- QKV projection (128x128 tile, 1-D grid, m-fastest for XCD locality) ----------------
// XCD = bid % 8 = m % 8 (32 m-tiles, 32 % 8 == 0): all 18 blocks (6 n x 3 w) sharing one
// x m-tile land on ONE XCD -> x re-reads hit that XCD's L2 instead of L3.
__global__ __launch_bounds__(256) void qkv_gemm(const u16* __restrict__ xb,
    const u16* __restrict__ Wqt, const u16* __restrict__ Wkt, const u16* __restrict__ Wvt,
    u16* __restrict__ qp, u16* __restrict__ kp, u16* __restrict__ ktp, u16* __restrict__ vtp) {
  __shared__ __attribute__((aligned(16))) char As[16384];
  __shared__ __attribute__((aligned(16))) char Zs[16384];
  int tid = threadIdx.x, lane = tid & 63, wid = tid >> 6;
  int quad = lane >> 4, l15 = lane & 15;
  int bid = blockIdx.x;
  int m0 = (bid & 31) * 128;
  int nw = bid >> 5;
  int n0 = (nw % 6) * 128, w = nw / 6;
  const u16* Zt = (w == 0) ? Wqt : (w == 1) ? Wkt : Wvt;
  int wm = wid >> 1, wn = wid & 1;
  f32x4 acc[4][4] = {};
  for (int kt = 0; kt < EE / 64; ++kt) {
    __syncthreads();
    stage_tile<128>(xb, EE, m0, kt * 64, As, tid);
    stage_tile<128>(Zt, EE, n0, kt * 64, Zs, tid);
    __syncthreads();
    short8 af[2][4], bfr[2][4];
#pragma unroll
    for (int ds = 0; ds < 2; ++ds) {
      int gk = ds * 4 + quad;
#pragma unroll
      for (int i = 0; i < 4; ++i) {
        af[ds][i]  = read_frag(As, wm * 64 + i * 16 + l15, gk);
        bfr[ds][i] = read_frag(Zs, wn * 64 + i * 16 + l15, gk);
      }
    }
#pragma unroll
    for (int mi = 0; mi < 4; ++mi)
#pragma unroll
      for (int ni = 0; ni < 4; ++ni) {
        acc[mi][ni] = __builtin_amdgcn_mfma_f32_16x16x32_bf16(af[0][mi], bfr[0][ni], acc[mi][ni], 0, 0, 0);
        acc[mi][ni] = __builtin_amdgcn_mfma_f32_16x16x32_bf16(af[1][mi], bfr[1][ni], acc[mi][ni], 0, 0, 0);
      }
  }
#pragma unroll
  for (int mi = 0; mi < 4; ++mi) {
    int mbase = m0 + wm * 64 + mi * 16 + (quad << 2);
    int bidx = mbase >> 11, nbase = mbase & 2047;
#pragma unroll
    for (int ni = 0; ni < 4; ++ni) {
      int e = n0 + wn * 64 + ni * 16 + l15;
      int h = e >> 6, d = e & 63;
      u16 v0 = f2bf(silu_f(acc[mi][ni][0]));
      u16 v1 = f2bf(silu_f(acc[mi][ni][1]));
      u16 v2 = f2bf(silu_f(acc[mi][ni][2]));
      u16 v3 = f2bf(silu_f(acc[mi][ni][3]));
      if (w < 2) {
        u16* dst = (w == 0 ? qp : kp) + (size_t)(bidx * HH + h) * NN * DD + d;
        dst[(size_t)(nbase + 0) * DD] = v0;
        dst[(size_t)(nbase + 1) * DD] = v1;
        dst[(size_t)(nbase + 2) * DD] = v2;
        dst[(size_t)(nbase + 3) * DD] = v3;
        if (w == 1) {  // K^T for lstate
          u16x4 pk; pk.x = v0; pk.y = v1; pk.z = v2; pk.w = v3;
          *(u16x4*)(ktp + (size_t)((bidx * HH + h) * DD + d) * NN + nbase) = pk;
        }
      } else {
        u16x4 pk; pk.x = v0; pk.y = v1; pk.z = v2; pk.w = v3;
        *(u16x4*)(vtp + (size_t)((bidx * HH + h) * DD + d) * NN + nbase) = pk;
      }
    }
  }
}

// ---------------- pass A: per-chunk local decayed KV state (fp32 out — R12's bf16 out
// regressed scan 17x via scratch-spilled u16x4 prefetch rings; reverted) ----------------
__global__ __launch_bounds__(256) void lstate_kernel(const u16* __restrict__ ktp,
    const u16* __restrict__ vtp, const float* __restrict__ slopes, float* __restrict__ Lst) {
  __shared__ __attribute__((aligned(16))) char KTs[8192];
  __shared__ __attribute__((aligned(16))) char VTs[8192];
  int tid = threadIdx.x, lane = tid & 63, wid = tid >> 6;
  int quad = lane >> 4, l15 = lane & 15;
  int c = blockIdx.x, bh = blockIdx.y, h = bh % HH;
  float slope = slopes[h];
  const u16* ktb = ktp + (size_t)bh * DD * NN;
  const u16* vtb = vtp + (size_t)bh * DD * NN;
  stage_tile<64>(vtb, NN, 0, c * 64, VTs, tid);
  stage_tile<64>(ktb, NN, 0, c * 64, KTs, tid);
  __syncthreads();
  f32x4 acc[4] = {};
  float em = __expf(-slope);  // > 1, <= ~1.9
#pragma unroll
  for (int ks = 0; ks < 2; ++ks) {
    int kg = ks * 4 + quad;
    short8 vf = read_frag(VTs, wid * 16 + l15, kg);
    float f = __expf(slope * (float)(64 - kg * 8));
    short8 vdf;
#pragma unroll
    for (int jj = 0; jj < 8; ++jj) { vdf[jj] = (short)f2bf(bf2f(vf[jj]) * f); f *= em; }
#pragma unroll
    for (int dt = 0; dt < 4; ++dt)
      acc[dt] = __builtin_amdgcn_mfma_f32_16x16x32_bf16(
          vdf, read_frag(KTs, dt * 16 + l15, kg), acc[dt], 0, 0, 0);
  }
  float* Lo = Lst + ((size_t)bh * 32 + c) * 4096;
#pragma unroll
  for (int dt = 0; dt < 4; ++dt)
#pragma unroll
    for (int r = 0; r < 4; ++r)
      Lo[(wid * 16 + quad * 4 + r) * 64 + dt * 16 + l15] = acc[dt][r];
}

// ---------------- scan: exclusive decayed prefix of chunk states (R11 version) ----------------
// S_{c+1} = S_c * e^{64s} + L_c; reads fp32 Lst, writes bf16 hi/lo planes to SEPARATE Sst
// (slot c holds S_{c+1}). No aliasing -> no barriers -> 8-deep float4 prefetch ring
// (16B-aligned fp32 aggregate stays register-promoted; R12's u16x4 rings spilled to
// scratch and cost 87 us).
__global__ __launch_bounds__(256) void scan_kernel(const float* __restrict__ Lst,
    float* __restrict__ Sst, const float* __restrict__ slopes) {
  int g = blockIdx.x, bh = blockIdx.y, h = bh % HH, t = threadIdx.x;
  float D = __expf(slopes[h] * 64.f);
  const float* base = Lst + (size_t)bh * 32 * 4096;
  float* obase = Sst + (size_t)bh * 32 * 4096;
  int off = g * 1024 + t * 4;
  float4 acc = {0.f, 0.f, 0.f, 0.f};
  float4 ring[8];
#pragma unroll
  for (int i = 0; i < 8; ++i) ring[i] = *(const float4*)(base + (size_t)i * 4096 + off);
  for (int c = 0; c < 31; ++c) {
    float4 cur = ring[c & 7];
    if (c + 8 < 31) ring[c & 7] = *(const float4*)(base + (size_t)(c + 8) * 4096 + off);
    acc.x = acc.x * D + cur.x;
    acc.y = acc.y * D + cur.y;
    acc.z = acc.z * D + cur.z;
    acc.w = acc.w * D + cur.w;
    float a[4] = {acc.x, acc.y, acc.z, acc.w};
    u16 hv[4], lv[4];
#pragma unroll
    for (int i = 0; i < 4; ++i) {
      hv[i] = f2bf(a[i]);
      lv[i] = f2bf(a[i] - bf2f((short)hv[i]));
    }
    u16x4 hi, lo;
    hi.x = hv[0]; hi.y = hv[1]; hi.z = hv[2]; hi.w = hv[3];
    lo.x = lv[0]; lo.y = lv[1]; lo.z = lv[2]; lo.w = lv[3];
    u16* sb = (u16*)(obase + (size_t)c * 4096);
    int wo = g * 2048 + (t >> 4) * 64 + (t & 15) * 4;
    *(u16x4*)(sb + wo) = hi;
    *(u16x4*)(sb + wo + 1024) = lo;
  }
}

// ---------------- pass B: intra-chunk attn + q_decayed @ S_prev + fused output gate ----------------
__global__ __launch_bounds__(256) void attn_chunk(const u16* __restrict__ qp,
    const u16* __restrict__ kp, const u16* __restrict__ vtp,
    const float* __restrict__ slopes, const float* __restrict__ Sst,
    const float* __restrict__ tgp, const float* __restrict__ Wg2, u16* __restrict__ attnb) {
  __shared__ __attribute__((aligned(16))) char Ks[8192];
  __shared__ __attribute__((aligned(16))) char Vs[8192];
  __shared__ __attribute__((aligned(16))) char Sh[8192];
  __shared__ __attribute__((aligned(16))) char Sl[8192];
  __shared__ __attribute__((aligned(16))) char Ps[4][2304];  // per-wave P, 16 rows x 144B stride
  __shared__ float ts[64][16];   // gate t rows for this q-chunk
  __shared__ float w2[16][64];   // Wg2 columns for this head
  int tid = threadIdx.x, lane = tid & 63, wid = tid >> 6;
  int quad = lane >> 4, l15 = lane & 15;
  int c = blockIdx.x, bh = blockIdx.y, b = bh / HH, h = bh % HH;
  float slope = slopes[h];
  int q0 = c * 64;
  const u16* qbh = qp + (size_t)bh * NN * DD;
  const u16* kbh = kp + (size_t)bh * NN * DD;
  const u16* vbh = vtp + (size_t)bh * DD * NN;

  stage_tile<64>(kbh, DD, q0, 0, Ks, tid);   // K chunk: 64 keys x 64 d
  stage_tile<64>(vbh, NN, 0, q0, Vs, tid);   // V^T chunk: 64 d x 64 keys
  if (c > 0) {
    const u16* sb = (const u16*)(Sst + ((size_t)bh * 32 + (c - 1)) * 4096);
    stage_S(sb, Sh, tid, 0);
    stage_S(sb, Sl, tid, 1);
  }
  // gate operands: t rows (64x16) and Wg2 slab (16x64)
  {
    float4 tv = *(const float4*)(tgp + ((size_t)(b * NN + q0) + (tid >> 2)) * GG + (tid & 3) * 4);
    *(float4*)&ts[tid >> 2][(tid & 3) * 4] = tv;
    float4 wv = *(const float4*)(Wg2 + (size_t)(tid >> 4) * EE + h * 64 + (tid & 15) * 4);
    *(float4*)&w2[tid >> 4][(tid & 15) * 4] = wv;
  }
  int qrow = q0 + wid * 16 + l15;
  short8 qf0 = *(const short8*)(qbh + (size_t)qrow * DD + (quad << 3));
  short8 qf1 = *(const short8*)(qbh + (size_t)qrow * DD + 32 + (quad << 3));
  __syncthreads();

  f32x4 oacc[4] = {};
  char* Pw = Ps[wid];
  int qbase = q0 + wid * 16 + (quad << 2);

  // ---- intra-chunk: S = QK^T . decay, P -> A-layout via wave-private LDS, O += P V
  float t_hi = (float)(q0 + 63);
  float rex[4];
#pragma unroll
  for (int r = 0; r < 4; ++r) rex[r] = __expf(slope * ((float)(qbase + r) - t_hi));
#pragma unroll
  for (int jt = 0; jt < 4; ++jt) {
    f32x4 s = {};
    s = __builtin_amdgcn_mfma_f32_16x16x32_bf16(qf0, read_frag(Ks, jt * 16 + l15, quad), s, 0, 0, 0);
    s = __builtin_amdgcn_mfma_f32_16x16x32_bf16(qf1, read_frag(Ks, jt * 16 + l15, 4 + quad), s, 0, 0, 0);
    int jg = q0 + jt * 16 + l15;
    float cex = __expf(slope * (t_hi - (float)jg));
#pragma unroll
    for (int r = 0; r < 4; ++r) {
      int diff = qbase + r - jg;
      float val = (diff >= 0) ? s[r] * rex[r] * cex : 0.f;
      *(u16*)(Pw + (((quad << 2) + r) * 72 + jt * 16 + l15) * 2) = f2bf(val);
    }
  }
  __asm__ volatile("s_waitcnt lgkmcnt(0)" ::: "memory");
#pragma unroll
  for (int ks = 0; ks < 2; ++ks) {
    short8 pf = *(const short8*)(Pw + l15 * 144 + ks * 64 + (quad << 4));
#pragma unroll
    for (int dt = 0; dt < 4; ++dt) {
      oacc[dt] = __builtin_amdgcn_mfma_f32_16x16x32_bf16(
          pf, read_frag(Vs, dt * 16 + l15, ks * 4 + quad), oacc[dt], 0, 0, 0);
    }
  }

  // ---- inter-chunk: O += (e^{s*il} q) @ S_prev  (hi + lo planes)
  if (c > 0) {
    int il = wid * 16 + l15;
    float qsc = __expf(slope * (float)il);
    short8 qd0 = scale_frag(qf0, qsc);
    short8 qd1 = scale_frag(qf1, qsc);
#pragma unroll
    for (int dt = 0; dt < 4; ++dt) {
      oacc[dt] = __builtin_amdgcn_mfma_f32_16x16x32_bf16(qd0, read_frag(Sh, dt * 16 + l15, quad), oacc[dt], 0, 0, 0);
      oacc[dt] = __builtin_amdgcn_mfma_f32_16x16x32_bf16(qd1, read_frag(Sh, dt * 16 + l15, 4 + quad), oacc[dt], 0, 0, 0);
      oacc[dt] = __builtin_amdgcn_mfma_f32_16x16x32_bf16(qd0, read_frag(Sl, dt * 16 + l15, quad), oacc[dt], 0, 0, 0);
      oacc[dt] = __builtin_amdgcn_mfma_f32_16x16x32_bf16(qd1, read_frag(Sl, dt * 16 + l15, 4 + quad), oacc[dt], 0, 0, 0);
    }
  }

  // ---- fused low-rank output gate: O *= sigmoid(t @ Wg2) for this head's slab
#pragma unroll
  for (int r = 0; r < 4; ++r) {
    int row = wid * 16 + (quad << 2) + r;
    float gv[4] = {0.f, 0.f, 0.f, 0.f};
#pragma unroll
    for (int g = 0; g < 16; ++g) {
      float tv = ts[row][g];
#pragma unroll
      for (int dt = 0; dt < 4; ++dt) gv[dt] += tv * w2[g][dt * 16 + l15];
    }
#pragma unroll
    for (int dt = 0; dt < 4; ++dt)
      oacc[dt][r] *= 1.f / (1.f + __expf(-gv[dt]));
  }

#pragma unroll
  for (int dt = 0; dt < 4; ++dt)
#pragma unroll
    for (int r = 0; r < 4; ++r) {
      int qi = qbase + r;
      int e = h * 64 + dt * 16 + l15;
      attnb[(size_t)(b * NN + qi) * EE + e] = f2bf(oacc[dt][r]);
    }
}

// ---------------- y = gated @ Wo (64x128 tile, 1-D grid m-fastest, bf16 out) ----------------
// XCD = bid % 8 = m % 8: the 6 n-blocks sharing an A m-tile co-locate on one XCD.
__global__ __launch_bounds__(256) void wo_gemm(const u16* __restrict__ A, const u16* __restrict__ Zt,
                                               u16* __restrict__ Y) {
  __shared__ __attribute__((aligned(16))) char As[8192];
  __shared__ __attribute__((aligned(16))) char Zs[16384];
  int tid = threadIdx.x, lane = tid & 63, wid = tid >> 6;
  int quad = lane >> 4, l15 = lane & 15;
  int bid = blockIdx.x;
  int m0 = (bid & 63) * 64, n0 = (bid >> 6) * 128;
  int wm = wid >> 1, wn = wid & 1;
  f32x4 acc[2][4] = {};
  for (int kt = 0; kt < EE / 64; ++kt) {
    __syncthreads();
    stage_tile<64>(A, EE, m0, kt * 64, As, tid);
    stage_tile<128>(Zt, EE, n0, kt * 64, Zs, tid);
    __syncthreads();
    short8 af[2][2], bfr[2][4];
#pragma unroll
    for (int ds = 0; ds < 2; ++ds) {
      int gk = ds * 4 + quad;
#pragma unroll
      for (int i = 0; i < 2; ++i)
        af[ds][i] = read_frag(As, wm * 32 + i * 16 + l15, gk);
#pragma unroll
      for (int i = 0; i < 4; ++i)
        bfr[ds][i] = read_frag(Zs, wn * 64 + i * 16 + l15, gk);
    }
#pragma unroll
    for (int mi = 0; mi < 2; ++mi)
#pragma unroll
      for (int ni = 0; ni < 4; ++ni) {
        acc[mi][ni] = __builtin_amdgcn_mfma_f32_16x16x32_bf16(af[0][mi], bfr[0][ni], acc[mi][ni], 0, 0, 0);
        acc[mi][ni] = __builtin_amdgcn_mfma_f32_16x16x32_bf16(af[1][mi], bfr[1][ni], acc[mi][ni], 0, 0, 0);
      }
  }
#pragma unroll
  for (int mi = 0; mi < 2; ++mi) {
    int mbase = m0 + wm * 32 + mi * 16 + (quad << 2);
#pragma unroll
    for (int ni = 0; ni < 4; ++ni) {
      int e = n0 + wn * 64 + ni * 16 + l15;
#pragma unroll
      for (int r = 0; r < 4; ++r)
        Y[(size_t)(mbase + r) * EE + e] = f2bf(acc[mi][ni][r]);
    }
  }
}

// ---------------- layernorm over E=768 (bf16 in, fp32 out), one block per row ----------------
__global__ __launch_bounds__(256) void ln_kernel(const u16* __restrict__ y, const float* __restrict__ w,
    const float* __restrict__ bb, float* __restrict__ out) {
  int m = blockIdx.x, tid = threadIdx.x;
  const u16* yr = y + (size_t)m * EE;
  float v0 = bf2f((short)yr[tid]), v1 = bf2f((short)yr[tid + 256]), v2 = bf2f((short)yr[tid + 512]);
  float s = v0 + v1 + v2;
  float s2 = v0 * v0 + v1 * v1 + v2 * v2;
#pragma unroll
  for (int off = 32; off > 0; off >>= 1) {
    s += __shfl_down(s, off);
    s2 += __shfl_down(s2, off);
  }
  __shared__ float ss[4], ssq[4];
  int lane = tid & 63, wid = tid >> 6;
  if (lane == 0) { ss[wid] = s; ssq[wid] = s2; }
  __syncthreads();
  s = ss[0] + ss[1] + ss[2] + ss[3];
  s2 = ssq[0] + ssq[1] + ssq[2] + ssq[3];
  float mu = s * (1.f / 768.f);
  float var = s2 * (1.f / 768.f) - mu * mu;
  float rs = rsqrtf(var + 1e-5f);
  float* orow = out + (size_t)m * EE;
  orow[tid]       = (v0 - mu) * rs * w[tid]       + bb[tid];
  orow[tid + 256] = (v1 - mu) * rs * w[tid + 256] + bb[tid + 256];
  orow[tid + 512] = (v2 - mu) * rs * w[tid + 512] + bb[tid + 512];
}

extern "C" void kernel_launch(void* const* d_in, const int* in_sizes, int n_in,
                              void* d_out, int out_size, void* d_ws, size_t ws_size,
                              hipStream_t stream) {
  (void)in_sizes; (void)n_in; (void)out_size; (void)ws_size;
  const float* x   = (const float*)d_in[0];
  const float* ls  = (const float*)d_in[1];
  const float* Wq  = (const float*)d_in[2];
  const float* Wk  = (const float*)d_in[3];
  const float* Wv  = (const float*)d_in[4];
  const float* Wo  = (const float*)d_in[5];
  const float* Wg1 = (const float*)d_in[6];
  const float* Wg2 = (const float*)d_in[7];
  const float* lnw = (const float*)d_in[8];
  const float* lnb = (const float*)d_in[9];

  // Workspace: high-water 61603840 B (ws proven 268 MB via fill WRITE_SIZE).
  char* p = (char*)d_ws;
  u16* xb    = (u16*)(p + 0);          // 6291456 B (xb -> attnb)
  u16* attnb = (u16*)(p + 0);
  u16* Wqt   = (u16*)(p + 6291456);
  u16* Wkt   = (u16*)(p + 7471104);
  u16* Wvt   = (u16*)(p + 8650752);
  u16* Wot   = (u16*)(p + 9830400);
  u16* qq    = (u16*)(p + 11010048);   // reused as yy (bf16) after attn
  u16* kk    = (u16*)(p + 17301504);
  u16* vt    = (u16*)(p + 23592960);
  float* tg  = (float*)(p + 29884416); // 262144 B
  float* Lst = (float*)(p + 30146560); // 12582912 B: fp32 chunk states L
  u16* kt2   = (u16*)(p + 42729472);   // 6291456 B: K^T
  float* Sst = (float*)(p + 49020928); // 12582912 B: bf16 hi/lo S planes (end 61603840)
  u16* yy    = (u16*)(p + 11010048);   // bf16 y (dead qq region)
  float* out = (float*)d_out;

  hipLaunchKernelGGL(prep_kernel, dim3(1600), dim3(256), 0, stream, x, Wq, Wk, Wv, Wo, Wg1,
                     xb, Wqt, Wkt, Wvt, Wot, tg);
  hipLaunchKernelGGL(qkv_gemm, dim3(576), dim3(256), 0, stream, xb, Wqt, Wkt, Wvt, qq, kk, kt2, vt);
  hipLaunchKernelGGL(lstate_kernel, dim3(32, 24), dim3(256), 0, stream, kt2, vt, ls, Lst);
  hipLaunchKernelGGL(scan_kernel, dim3(4, 24), dim3(256), 0, stream, Lst, Sst, ls);
  hipLaunchKernelGGL(attn_chunk, dim3(32, 24), dim3(256), 0, stream, qq, kk, vt, ls, Sst, tg, Wg2, attnb);
  hipLaunchKernelGGL(wo_gemm, dim3(384), dim3(256), 0, stream, attnb, Wot, yy);
  hipLaunchKernelGGL(ln_kernel, dim3(4096), dim3(256), 0, stream, yy, lnw, lnb, out);
}